// Round 15
// baseline (165.637 us; speedup 1.0000x reference)
//
#include <hip/hip_runtime.h>

// SelfAttentionNarrow: B=4, T=2048, EMB=1024, H=16, S=64.
// r15: prep kernel ELIMINATED (4 dispatches -> 3). qkv converts Wk/Wq/Wv
// f32->f16 fragments in-register (weights L2-hot, +2 cvt-mul per fragment,
// hidden under memory); Wu conversion folded into qkv grid as 64 extra
// blocks (blockIdx.x==32). flash frozen (additive-pipe floor ~80us:
// MFMA 29 + VALU 34 + LDS 15 ~= 78 ~= observed); oproj frozen at r14.

typedef float f32x4 __attribute__((ext_vector_type(4)));
typedef float f32x16 __attribute__((ext_vector_type(16)));
typedef _Float16 f16x2 __attribute__((ext_vector_type(2)));
typedef _Float16 f16x8 __attribute__((ext_vector_type(8)));
typedef unsigned u32x4 __attribute__((ext_vector_type(4)));

#define MFMA16(a, b, c) __builtin_amdgcn_mfma_f32_16x16x32_f16((a), (b), (c), 0, 0, 0)
#define MFMA32(a, b, c) __builtin_amdgcn_mfma_f32_32x32x16_f16((a), (b), (c), 0, 0, 0)

constexpr int Tn = 2048;
constexpr int Bn = 4;
constexpr int EMBn = 1024;
constexpr float NEG_INF = -3.0e38f;

__device__ __forceinline__ float exp2_hw(float x) {
  float r; asm("v_exp_f32 %0, %1" : "=v"(r) : "v"(x)); return r;
}
__device__ __forceinline__ unsigned pkrtz(float lo, float hi) {
  unsigned r; asm("v_cvt_pkrtz_f16_f32 %0, %1, %2" : "=v"(r) : "v"(lo), "v"(hi)); return r;
}
__device__ __forceinline__ unsigned pkadd(unsigned a, unsigned b) {
  unsigned r; asm("v_pk_add_f16 %0, %1, %2" : "=v"(r) : "v"(a), "v"(b)); return r;
}
__device__ __forceinline__ void permswap(unsigned& a, unsigned& b) {
  asm("v_permlane32_swap_b32 %0, %1" : "+v"(a), "+v"(b));
}
__device__ __forceinline__ void glds16(const void* g, void* l) {
  __builtin_amdgcn_global_load_lds(
      (const __attribute__((address_space(1))) unsigned*)g,
      (__attribute__((address_space(3))) unsigned*)l, 16, 0, 0);
}
// 8 consecutive f32 -> f16x8 with scale (RNE via compiler cvt)
__device__ __forceinline__ f16x8 wf16(const float* p, float s) {
  f32x4 u = *(const f32x4*)p;
  f32x4 v = *(const f32x4*)(p + 4);
  f16x8 a;
  a[0] = (_Float16)(u[0] * s); a[1] = (_Float16)(u[1] * s);
  a[2] = (_Float16)(u[2] * s); a[3] = (_Float16)(u[3] * s);
  a[4] = (_Float16)(v[0] * s); a[5] = (_Float16)(v[1] * s);
  a[6] = (_Float16)(v[2] * s); a[7] = (_Float16)(v[3] * s);
  return a;
}

// ----------------------------------------------------------------- qkv ----
// grid (33, 64). x<32: QKV for 64 t of head blockIdx.y, f32 weights
// converted in-register. x==32: this y-slice converts 16384 Wu elements.
__global__ __launch_bounds__(256) void sa_qkv(
    const float* __restrict__ x,
    const float* __restrict__ Wk, const float* __restrict__ Wq,
    const float* __restrict__ Wv, const float* __restrict__ Wu,
    _Float16* __restrict__ Qb, _Float16* __restrict__ Kb,
    _Float16* __restrict__ Vt, _Float16* __restrict__ wub) {
  const int tid = threadIdx.x;

  if (blockIdx.x == 32) {   // ---- folded Wu f32->f16 conversion ----
    long base = (long)blockIdx.y * 16384;
#pragma unroll
    for (int ch = 0; ch < 4; ++ch) {
      long e0 = base + (ch * 256 + tid) * 16;
      f32x4 a = *(const f32x4*)(Wu + e0);
      f32x4 b = *(const f32x4*)(Wu + e0 + 4);
      f32x4 c = *(const f32x4*)(Wu + e0 + 8);
      f32x4 d = *(const f32x4*)(Wu + e0 + 12);
      u32x4 o0 = {pkrtz(a[0], a[1]), pkrtz(a[2], a[3]),
                  pkrtz(b[0], b[1]), pkrtz(b[2], b[3])};
      u32x4 o1 = {pkrtz(c[0], c[1]), pkrtz(c[2], c[3]),
                  pkrtz(d[0], d[1]), pkrtz(d[2], d[3])};
      *(u32x4*)(wub + e0) = o0;
      *(u32x4*)(wub + e0 + 8) = o1;
    }
    return;
  }

  const int wave = tid >> 6;
  const int lane = tid & 63;
  const int g = lane >> 4, c = lane & 15;
  const int n = blockIdx.y, b = n >> 4, h = n & 15;
  const int t0 = blockIdx.x * 64;
  const int tw = t0 + wave * 16;
  const float rs = 0.21233046f;  // sqrt(log2(e)/32): logits in log2 units

  __shared__ __align__(16) _Float16 sm[3 * 64 * 72];  // K @0, Q @4608, V @9216
  _Float16* smK = sm;
  _Float16* smQ = sm + 4608;
  _Float16* smV = sm + 9216;

  f16x8 ax[2];
#pragma unroll
  for (int kk = 0; kk < 2; ++kk) {
    const float* xp = x + ((long)((b * Tn + tw + c) * 16 + h)) * 64 + kk * 32 + g * 8;
    ax[kk] = wf16(xp, 1.0f);
  }

  // K (w=0), Q (w=1): D[t][o]; LDS row = t-local, col = o
#pragma unroll
  for (int w = 0; w < 2; ++w) {
    const float* Wsrc = w ? Wq : Wk;
    _Float16* dst = w ? smQ : smK;
#pragma unroll
    for (int ot = 0; ot < 4; ++ot) {
      f32x4 a_ = {0.f, 0.f, 0.f, 0.f};
#pragma unroll
      for (int kk = 0; kk < 2; ++kk) {
        f16x8 wf = wf16(Wsrc + (ot * 16 + c) * 64 + kk * 32 + g * 8, rs);
        a_ = MFMA16(ax[kk], wf, a_);
      }
#pragma unroll
      for (int r = 0; r < 4; ++r)
        dst[(wave * 16 + g * 4 + r) * 72 + ot * 16 + c] = (_Float16)a_[r];
    }
  }

  // V^T: D[o][t]; LDS row = o, col = t-local
#pragma unroll
  for (int ot = 0; ot < 4; ++ot) {
    f32x4 a_ = {0.f, 0.f, 0.f, 0.f};
#pragma unroll
    for (int kk = 0; kk < 2; ++kk) {
      f16x8 wf = wf16(Wv + (ot * 16 + c) * 64 + kk * 32 + g * 8, 1.0f);
      a_ = MFMA16(wf, ax[kk], a_);
    }
#pragma unroll
    for (int r = 0; r < 4; ++r)
      smV[(ot * 16 + g * 4 + r) * 72 + wave * 16 + c] = (_Float16)a_[r];
  }

  __syncthreads();

  const int sl = tid & 7;
#pragma unroll
  for (int j = 0; j < 2; ++j) {
    int row = j * 32 + (tid >> 3);
    f16x8 kv = *(const f16x8*)(smK + row * 72 + sl * 8);
    f16x8 qv = *(const f16x8*)(smQ + row * 72 + sl * 8);
    f16x8 vv = *(const f16x8*)(smV + row * 72 + sl * 8);
    *(f16x8*)(Kb + ((long)n * Tn + t0 + row) * 64 + sl * 8) = kv;
    *(f16x8*)(Qb + ((long)n * Tn + t0 + row) * 64 + sl * 8) = qv;
    *(f16x8*)(Vt + ((long)n * 64 + row) * Tn + t0 + sl * 8) = vv;
  }
}

// --------------------------------------------------------------- flash ----
// r11 form, frozen.
__global__ __launch_bounds__(256, 2) void sa_flash(
    const _Float16* __restrict__ Qb, const _Float16* __restrict__ Kb,
    const _Float16* __restrict__ Vt, const int* __restrict__ pad32,
    _Float16* __restrict__ AO) {
  const int bid = blockIdx.x;
  const int n = (bid & 7) * 8 + (bid >> 6);      // head
  const int qblk = (bid >> 3) & 7;
  const int tid = threadIdx.x;
  const int wave = tid >> 6;
  const int lane = tid & 63;
  const int ql = lane & 31;
  const int hi = lane >> 5;

  int thresh = Tn;
  if (n < Bn) {
    bool is64 = (pad32[1] == 0 && pad32[3] == 0);
    int pv = is64 ? pad32[2 * n] : pad32[n];
    thresh = Tn - pv;
  }

  const int qbase = qblk * 256 + wave * 64;
  const _Float16* Qh = Qb + (long)n * Tn * 64;
  const _Float16* Kh = Kb + (long)n * Tn * 64;
  const _Float16* Vh = Vt + (long)n * 64 * Tn;

  f16x8 bq[2][4];
#pragma unroll
  for (int qh = 0; qh < 2; ++qh) {
    const _Float16* qp = Qh + (long)(qbase + qh * 32 + ql) * 64 + hi * 8;
#pragma unroll
    for (int ks = 0; ks < 4; ++ks) bq[qh][ks] = *(const f16x8*)(qp + ks * 16);
  }

  __shared__ __align__(16) char smem[32768];

  const int srow = wave * 16 + (lane >> 3);
  const int sswz = ((lane & 7) ^ (lane >> 3)) * 8;
  const _Float16* ksrc = Kh + (long)srow * 64 + sswz;
  const _Float16* vsrc = Vh + (long)srow * Tn + sswz;

  f32x16 o[2][2];
  f32x16 zf;
#pragma unroll
  for (int i = 0; i < 16; ++i) {
    o[0][0][i] = 0.f; o[0][1][i] = 0.f; o[1][0][i] = 0.f; o[1][1][i] = 0.f;
    zf[i] = 0.f;
  }
  float l0 = 0.f, l1 = 0.f;

  const bool qge0 = (qbase + ql) >= thresh;
  const bool qge1 = (qbase + 32 + ql) >= thresh;
  const bool qany = (qbase + 64) > thresh;
  const int sw = ql & 7;

  {
    char* kd = smem + wave * 2048;
    char* vd = smem + 16384 + wave * 2048;
    glds16(ksrc, kd);
    glds16(ksrc + 512, kd + 1024);
    glds16(vsrc, vd);
    glds16(vsrc + 8 * Tn, vd + 1024);
  }
  __syncthreads();

  int cur = 0;
  for (int kb = 0; kb < Tn; kb += 64) {
    const int kbn = (kb + 64) & (Tn - 1);
    {
      char* kd = smem + (cur ^ 1) * 8192 + wave * 2048;
      char* vd = smem + 16384 + (cur ^ 1) * 8192 + wave * 2048;
      glds16(ksrc + kbn * 64, kd);
      glds16(ksrc + kbn * 64 + 512, kd + 1024);
      glds16(vsrc + kbn, vd);
      glds16(vsrc + kbn + 8 * Tn, vd + 1024);
    }

    const char* kbb = smem + cur * 8192;
    const char* vbb = smem + 16384 + cur * 8192;

#pragma unroll
    for (int sub = 0; sub < 2; ++sub) {
      const char* krow = kbb + (sub * 32 + ql) * 128;
      f16x8 ka0 = *(const f16x8*)(krow + (((0 + hi) ^ sw) * 16));
      f16x8 ka1 = *(const f16x8*)(krow + (((2 + hi) ^ sw) * 16));
      f16x8 ka2 = *(const f16x8*)(krow + (((4 + hi) ^ sw) * 16));
      f16x8 ka3 = *(const f16x8*)(krow + (((6 + hi) ^ sw) * 16));

      __builtin_amdgcn_s_setprio(1);
      f32x16 st0 = MFMA32(ka0, bq[0][0], zf);
      f32x16 st1 = MFMA32(ka0, bq[1][0], zf);
      st0 = MFMA32(ka1, bq[0][1], st0);
      st1 = MFMA32(ka1, bq[1][1], st1);
      st0 = MFMA32(ka2, bq[0][2], st0);
      st1 = MFMA32(ka2, bq[1][2], st1);
      st0 = MFMA32(ka3, bq[0][3], st0);
      st1 = MFMA32(ka3, bq[1][3], st1);
      __builtin_amdgcn_s_setprio(0);

      if (qany && (kb + sub * 32 + 32) > thresh) {
#pragma unroll
        for (int r = 0; r < 16; ++r) {
          int kr_ = kb + sub * 32 + (r & 3) + 8 * (r >> 2) + 4 * hi;
          if (kr_ >= thresh) {
            if (qge0) st0[r] = NEG_INF;
            if (qge1) st1[r] = NEG_INF;
          }
        }
      }

      const char* vrow0 = vbb + ql * 128;
      const char* vrow1 = vbb + (ql + 32) * 128;
      f16x8 va0 = *(const f16x8*)(vrow0 + (((sub * 4 + hi) ^ sw) * 16));
      f16x8 va1 = *(const f16x8*)(vrow0 + (((sub * 4 + 2 + hi) ^ sw) * 16));
      f16x8 va2 = *(const f16x8*)(vrow1 + (((sub * 4 + hi) ^ sw) * 16));
      f16x8 va3 = *(const f16x8*)(vrow1 + (((sub * 4 + 2 + hi) ^ sw) * 16));

#pragma unroll
      for (int qh = 0; qh < 2; ++qh) {
        const f32x16& stq = qh ? st1 : st0;
        float p[16];
#pragma unroll
        for (int r = 0; r < 16; ++r) p[r] = exp2_hw(stq[r]);

        unsigned pw[8], psum[2];
#pragma unroll
        for (int j = 0; j < 2; ++j) {
          unsigned a0 = pkrtz(p[j * 8 + 0], p[j * 8 + 1]);
          unsigned b0 = pkrtz(p[j * 8 + 4], p[j * 8 + 5]);
          unsigned a1 = pkrtz(p[j * 8 + 2], p[j * 8 + 3]);
          unsigned b1 = pkrtz(p[j * 8 + 6], p[j * 8 + 7]);
          psum[j] = pkadd(pkadd(a0, b0), pkadd(a1, b1));
          permswap(a0, b0);
          permswap(a1, b1);
          pw[j * 4 + 0] = a0; pw[j * 4 + 1] = a1;
          pw[j * 4 + 2] = b0; pw[j * 4 + 3] = b1;
        }
        {
          f16x2 ph = __builtin_bit_cast(f16x2, pkadd(psum[0], psum[1]));
          if (qh) l1 += (float)ph[0] + (float)ph[1];
          else    l0 += (float)ph[0] + (float)ph[1];
        }
        u32x4 u0 = {pw[0], pw[1], pw[2], pw[3]};
        u32x4 u1 = {pw[4], pw[5], pw[6], pw[7]};
        f16x8 pb0 = __builtin_bit_cast(f16x8, u0);
        f16x8 pb1 = __builtin_bit_cast(f16x8, u1);

        __builtin_amdgcn_s_setprio(1);
        o[qh][0] = MFMA32(va0, pb0, o[qh][0]);
        o[qh][0] = MFMA32(va1, pb1, o[qh][0]);
        o[qh][1] = MFMA32(va2, pb0, o[qh][1]);
        o[qh][1] = MFMA32(va3, pb1, o[qh][1]);
        __builtin_amdgcn_s_setprio(0);
      }
    }

    __syncthreads();
    cur ^= 1;
  }

  float lf0 = l0 + __shfl_xor(l0, 32, 64);
  float lf1 = l1 + __shfl_xor(l1, 32, 64);
  float linv0 = 1.0f / lf0;
  float linv1 = 1.0f / lf1;

  const int bb = n >> 4, hh = n & 15;
  const int qr = lane >> 3, s0 = (lane & 7) * 8;
  _Float16* my = (_Float16*)(smem + wave * 8192);
#pragma unroll
  for (int qh = 0; qh < 2; ++qh) {
    float linv = qh ? linv1 : linv0;
    _Float16* myq = my + qh * 2048;
#pragma unroll
    for (int stile = 0; stile < 2; ++stile) {
#pragma unroll
      for (int r = 0; r < 16; r += 2) {
        unsigned wv = pkrtz(o[qh][stile][r] * linv, o[qh][stile][r + 1] * linv);
        int s = stile * 32 + (r & 3) + 8 * (r >> 2) + 4 * hi;
        *(unsigned*)(myq + ql * 64 + (s ^ ((ql & 7) << 3))) = wv;
      }
    }
  }
  asm volatile("s_waitcnt lgkmcnt(0)" ::: "memory");

#pragma unroll
  for (int qh = 0; qh < 2; ++qh) {
    _Float16* myq = my + qh * 2048;
#pragma unroll
    for (int j = 0; j < 4; ++j) {
      int q = j * 8 + qr;
      f16x8 vv = *(const f16x8*)(myq + q * 64 + (s0 ^ ((q & 7) << 3)));
      *(f16x8*)(AO + ((long)(bb * Tn + qbase + qh * 32 + q)) * EMBn + hh * 64 + s0) = vv;
    }
  }
}

// --------------------------------------------------------------- oproj ----
// r14 form, frozen: 1024 blocks, 128m x 64n, lb(256,4), A-frag dbuf.
__global__ __launch_bounds__(256, 4) void sa_oproj(
    const _Float16* __restrict__ A, const _Float16* __restrict__ WuB,
    const float* __restrict__ bu, float* __restrict__ Y) {
  const int bid = blockIdx.x;
  const int xcd = bid & 7;
  const int j = bid >> 3;             // 0..127
  const int nstrip = j & 15;
  const int mblk = xcd * 8 + (j >> 4);
  const int tid = threadIdx.x;
  const int wave = tid >> 6;
  const int lane = tid & 63;
  const int ql = lane & 31;
  const int hi = lane >> 5;
  const int mbase = mblk * 128 + wave * 32;
  const int nbase = nstrip * 64;

  __shared__ __align__(16) char bsm[18432];
  const int sr = tid >> 3, sc = tid & 7;
  const _Float16* wg0 = WuB + (long)(nbase + sr) * 1024 + sc * 8;
  const _Float16* wg1 = WuB + (long)(nbase + sr + 32) * 1024 + sc * 8;
  char* ww0 = bsm + sr * 144 + sc * 16;
  char* ww1 = bsm + (sr + 32) * 144 + sc * 16;

  const _Float16* ap = A + (long)(mbase + ql) * 1024 + hi * 8;

  f32x16 acc[2];
#pragma unroll
  for (int i = 0; i < 16; ++i) { acc[0][i] = 0.f; acc[1][i] = 0.f; }

  f16x8 af[4];
  {
    f16x8 w0 = *(const f16x8*)wg0;
    f16x8 w1 = *(const f16x8*)wg1;
    *(f16x8*)ww0 = w0;
    *(f16x8*)ww1 = w1;
#pragma unroll
    for (int ks = 0; ks < 4; ++ks) af[ks] = *(const f16x8*)(ap + ks * 16);
  }
  __syncthreads();

  int cur = 0;
  for (int kb = 0; kb < 1024; kb += 64) {
    const int kbn = (kb + 64) & 1023;
    f16x8 wn0 = *(const f16x8*)(wg0 + kbn);
    f16x8 wn1 = *(const f16x8*)(wg1 + kbn);
    f16x8 an[4];
#pragma unroll
    for (int ks = 0; ks < 4; ++ks) an[ks] = *(const f16x8*)(ap + kbn + ks * 16);

    const char* bbase = bsm + cur * 9216;
#pragma unroll
    for (int nt = 0; nt < 2; ++nt) {
      const char* brow = bbase + (nt * 32 + ql) * 144;
#pragma unroll
      for (int ks = 0; ks < 4; ++ks) {
        f16x8 bf = *(const f16x8*)(brow + (ks * 2 + hi) * 16);
        acc[nt] = MFMA32(af[ks], bf, acc[nt]);
      }
    }

    *(f16x8*)(ww0 + (cur ^ 1) * 9216) = wn0;
    *(f16x8*)(ww1 + (cur ^ 1) * 9216) = wn1;
    __syncthreads();
#pragma unroll
    for (int ks = 0; ks < 4; ++ks) af[ks] = an[ks];
    cur ^= 1;
  }

#pragma unroll
  for (int nt = 0; nt < 2; ++nt) {
    float bias = bu[nbase + nt * 32 + ql];
#pragma unroll
    for (int r = 0; r < 16; ++r) {
      int mrow = mbase + (r & 3) + 8 * (r >> 2) + 4 * hi;
      Y[(long)mrow * 1024 + nbase + nt * 32 + ql] = acc[nt][r] + bias;
    }
  }
}

// -------------------------------------------------------------- launch ----
extern "C" void kernel_launch(void* const* d_in, const int* in_sizes, int n_in,
                              void* d_out, int out_size, void* d_ws, size_t ws_size,
                              hipStream_t stream) {
  const float* x  = (const float*)d_in[0];
  const float* Wk = (const float*)d_in[1];
  const float* Wq = (const float*)d_in[2];
  const float* Wv = (const float*)d_in[3];
  const float* Wu = (const float*)d_in[4];
  const float* bu = (const float*)d_in[5];
  const int* pad  = (const int*)d_in[6];
  float* Y = (float*)d_out;

  _Float16* ws  = (_Float16*)d_ws;
  _Float16* wub = ws;                        // 1048576
  _Float16* Qb  = ws + 1048576;              // 8388608 each
  _Float16* Kb  = Qb + 8388608;
  _Float16* Vt  = Kb + 8388608;              // V transposed: [n][s][t]
  _Float16* AO  = Vt + 8388608;

  sa_qkv<<<dim3(33, 64), 256, 0, stream>>>(x, Wk, Wq, Wv, Wu, Qb, Kb, Vt, wub);
  sa_flash<<<dim3(512), 256, 0, stream>>>(Qb, Kb, Vt, pad, AO);
  sa_oproj<<<dim3(1024), 256, 0, stream>>>(AO, wub, bu, Y);
}

// Round 16
// 146.030 us; speedup vs baseline: 1.1343x; 1.1343x over previous
//
#include <hip/hip_runtime.h>

// SelfAttentionNarrow: B=4, T=2048, EMB=1024, H=16, S=64.
// r16: pure revert to r14 (best measured: 146.1us). r15's prep-elimination
// regressed +20us: per-block in-register weight conversion turned a 100KB
// one-time f16 table into ~400MB of redundant scattered L2 reads + VALU cvt.
// Pipeline: prep (vectorized) -> qkv (LDS-transposed coalesced epilogue) ->
// flash (frozen: additive-pipe floor ~80us) -> oproj (A-frag dbuf, 4 blk/CU).

typedef float f32x4 __attribute__((ext_vector_type(4)));
typedef float f32x16 __attribute__((ext_vector_type(16)));
typedef _Float16 f16x2 __attribute__((ext_vector_type(2)));
typedef _Float16 f16x8 __attribute__((ext_vector_type(8)));
typedef unsigned u32x4 __attribute__((ext_vector_type(4)));

#define MFMA16(a, b, c) __builtin_amdgcn_mfma_f32_16x16x32_f16((a), (b), (c), 0, 0, 0)
#define MFMA32(a, b, c) __builtin_amdgcn_mfma_f32_32x32x16_f16((a), (b), (c), 0, 0, 0)

constexpr int Tn = 2048;
constexpr int Bn = 4;
constexpr int EMBn = 1024;
constexpr float NEG_INF = -3.0e38f;

__device__ __forceinline__ float exp2_hw(float x) {
  float r; asm("v_exp_f32 %0, %1" : "=v"(r) : "v"(x)); return r;
}
__device__ __forceinline__ unsigned pkrtz(float lo, float hi) {
  unsigned r; asm("v_cvt_pkrtz_f16_f32 %0, %1, %2" : "=v"(r) : "v"(lo), "v"(hi)); return r;
}
__device__ __forceinline__ unsigned pkadd(unsigned a, unsigned b) {
  unsigned r; asm("v_pk_add_f16 %0, %1, %2" : "=v"(r) : "v"(a), "v"(b)); return r;
}
__device__ __forceinline__ void permswap(unsigned& a, unsigned& b) {
  asm("v_permlane32_swap_b32 %0, %1" : "+v"(a), "+v"(b));
}
__device__ __forceinline__ void glds16(const void* g, void* l) {
  __builtin_amdgcn_global_load_lds(
      (const __attribute__((address_space(1))) unsigned*)g,
      (__attribute__((address_space(3))) unsigned*)l, 16, 0, 0);
}

// ---------------------------------------------------------------- prep ----
// 1024 blocks. Wu: float4 -> 2x pkrtz -> 8B store. w3 scalar (tiny).
__global__ __launch_bounds__(256) void sa_prep(
    const float* __restrict__ Wk, const float* __restrict__ Wq,
    const float* __restrict__ Wv, const float* __restrict__ Wu,
    _Float16* __restrict__ w3, _Float16* __restrict__ wub) {
  int idx = blockIdx.x * 256 + threadIdx.x;
  const float rs = 0.21233046f;  // sqrt(log2(e) / 32): logits in log2 units
  if (idx < 262144) {
    f32x4 w = ((const f32x4*)Wu)[idx];
    unsigned r0 = pkrtz(w[0], w[1]);
    unsigned r1 = pkrtz(w[2], w[3]);
    unsigned* dst = (unsigned*)(wub + idx * 4);
    dst[0] = r0;
    dst[1] = r1;
  }
  if (idx < 4096) {
    w3[idx]        = (_Float16)(Wk[idx] * rs);
    w3[4096 + idx] = (_Float16)(Wq[idx] * rs);
    w3[8192 + idx] = (_Float16)(Wv[idx]);
  }
}

// ----------------------------------------------------------------- qkv ----
// r13 form: LDS-transposed epilogue, fully coalesced stores.
__global__ __launch_bounds__(256) void sa_qkv(
    const float* __restrict__ x, const _Float16* __restrict__ w3,
    _Float16* __restrict__ Qb, _Float16* __restrict__ Kb, _Float16* __restrict__ Vt) {
  const int tid = threadIdx.x;
  const int wave = tid >> 6;
  const int lane = tid & 63;
  const int g = lane >> 4, c = lane & 15;
  const int n = blockIdx.y, b = n >> 4, h = n & 15;
  const int t0 = blockIdx.x * 64;
  const int tw = t0 + wave * 16;

  __shared__ __align__(16) _Float16 sm[3 * 64 * 72];  // K @0, Q @4608, V @9216
  _Float16* smK = sm;
  _Float16* smQ = sm + 4608;
  _Float16* smV = sm + 9216;

  f16x8 ax[2];
#pragma unroll
  for (int kk = 0; kk < 2; ++kk) {
    const float* xp = x + ((long)((b * Tn + tw + c) * 16 + h)) * 64 + kk * 32 + g * 8;
    f32x4 u = *(const f32x4*)xp;
    f32x4 v = *(const f32x4*)(xp + 4);
    f16x8 a;
    a[0] = (_Float16)u[0]; a[1] = (_Float16)u[1]; a[2] = (_Float16)u[2]; a[3] = (_Float16)u[3];
    a[4] = (_Float16)v[0]; a[5] = (_Float16)v[1]; a[6] = (_Float16)v[2]; a[7] = (_Float16)v[3];
    ax[kk] = a;
  }

#pragma unroll
  for (int w = 0; w < 2; ++w) {
    _Float16* dst = w ? smQ : smK;
#pragma unroll
    for (int ot = 0; ot < 4; ++ot) {
      f32x4 a_ = {0.f, 0.f, 0.f, 0.f};
#pragma unroll
      for (int kk = 0; kk < 2; ++kk) {
        f16x8 wf = *(const f16x8*)(w3 + w * 4096 + (ot * 16 + c) * 64 + kk * 32 + g * 8);
        a_ = MFMA16(ax[kk], wf, a_);
      }
#pragma unroll
      for (int r = 0; r < 4; ++r)
        dst[(wave * 16 + g * 4 + r) * 72 + ot * 16 + c] = (_Float16)a_[r];
    }
  }

#pragma unroll
  for (int ot = 0; ot < 4; ++ot) {
    f32x4 a_ = {0.f, 0.f, 0.f, 0.f};
#pragma unroll
    for (int kk = 0; kk < 2; ++kk) {
      f16x8 wf = *(const f16x8*)(w3 + 8192 + (ot * 16 + c) * 64 + kk * 32 + g * 8);
      a_ = MFMA16(wf, ax[kk], a_);
    }
#pragma unroll
    for (int r = 0; r < 4; ++r)
      smV[(ot * 16 + g * 4 + r) * 72 + wave * 16 + c] = (_Float16)a_[r];
  }

  __syncthreads();

  const int sl = tid & 7;
#pragma unroll
  for (int j = 0; j < 2; ++j) {
    int row = j * 32 + (tid >> 3);
    f16x8 kv = *(const f16x8*)(smK + row * 72 + sl * 8);
    f16x8 qv = *(const f16x8*)(smQ + row * 72 + sl * 8);
    f16x8 vv = *(const f16x8*)(smV + row * 72 + sl * 8);
    *(f16x8*)(Kb + ((long)n * Tn + t0 + row) * 64 + sl * 8) = kv;
    *(f16x8*)(Qb + ((long)n * Tn + t0 + row) * 64 + sl * 8) = qv;
    *(f16x8*)(Vt + ((long)n * 64 + row) * Tn + t0 + sl * 8) = vv;
  }
}

// --------------------------------------------------------------- flash ----
// r11 form, frozen.
__global__ __launch_bounds__(256, 2) void sa_flash(
    const _Float16* __restrict__ Qb, const _Float16* __restrict__ Kb,
    const _Float16* __restrict__ Vt, const int* __restrict__ pad32,
    _Float16* __restrict__ AO) {
  const int bid = blockIdx.x;
  const int n = (bid & 7) * 8 + (bid >> 6);      // head
  const int qblk = (bid >> 3) & 7;
  const int tid = threadIdx.x;
  const int wave = tid >> 6;
  const int lane = tid & 63;
  const int ql = lane & 31;
  const int hi = lane >> 5;

  int thresh = Tn;
  if (n < Bn) {
    bool is64 = (pad32[1] == 0 && pad32[3] == 0);
    int pv = is64 ? pad32[2 * n] : pad32[n];
    thresh = Tn - pv;
  }

  const int qbase = qblk * 256 + wave * 64;
  const _Float16* Qh = Qb + (long)n * Tn * 64;
  const _Float16* Kh = Kb + (long)n * Tn * 64;
  const _Float16* Vh = Vt + (long)n * 64 * Tn;

  f16x8 bq[2][4];
#pragma unroll
  for (int qh = 0; qh < 2; ++qh) {
    const _Float16* qp = Qh + (long)(qbase + qh * 32 + ql) * 64 + hi * 8;
#pragma unroll
    for (int ks = 0; ks < 4; ++ks) bq[qh][ks] = *(const f16x8*)(qp + ks * 16);
  }

  __shared__ __align__(16) char smem[32768];

  const int srow = wave * 16 + (lane >> 3);
  const int sswz = ((lane & 7) ^ (lane >> 3)) * 8;
  const _Float16* ksrc = Kh + (long)srow * 64 + sswz;
  const _Float16* vsrc = Vh + (long)srow * Tn + sswz;

  f32x16 o[2][2];
  f32x16 zf;
#pragma unroll
  for (int i = 0; i < 16; ++i) {
    o[0][0][i] = 0.f; o[0][1][i] = 0.f; o[1][0][i] = 0.f; o[1][1][i] = 0.f;
    zf[i] = 0.f;
  }
  float l0 = 0.f, l1 = 0.f;

  const bool qge0 = (qbase + ql) >= thresh;
  const bool qge1 = (qbase + 32 + ql) >= thresh;
  const bool qany = (qbase + 64) > thresh;
  const int sw = ql & 7;

  {
    char* kd = smem + wave * 2048;
    char* vd = smem + 16384 + wave * 2048;
    glds16(ksrc, kd);
    glds16(ksrc + 512, kd + 1024);
    glds16(vsrc, vd);
    glds16(vsrc + 8 * Tn, vd + 1024);
  }
  __syncthreads();

  int cur = 0;
  for (int kb = 0; kb < Tn; kb += 64) {
    const int kbn = (kb + 64) & (Tn - 1);
    {
      char* kd = smem + (cur ^ 1) * 8192 + wave * 2048;
      char* vd = smem + 16384 + (cur ^ 1) * 8192 + wave * 2048;
      glds16(ksrc + kbn * 64, kd);
      glds16(ksrc + kbn * 64 + 512, kd + 1024);
      glds16(vsrc + kbn, vd);
      glds16(vsrc + kbn + 8 * Tn, vd + 1024);
    }

    const char* kbb = smem + cur * 8192;
    const char* vbb = smem + 16384 + cur * 8192;

#pragma unroll
    for (int sub = 0; sub < 2; ++sub) {
      const char* krow = kbb + (sub * 32 + ql) * 128;
      f16x8 ka0 = *(const f16x8*)(krow + (((0 + hi) ^ sw) * 16));
      f16x8 ka1 = *(const f16x8*)(krow + (((2 + hi) ^ sw) * 16));
      f16x8 ka2 = *(const f16x8*)(krow + (((4 + hi) ^ sw) * 16));
      f16x8 ka3 = *(const f16x8*)(krow + (((6 + hi) ^ sw) * 16));

      __builtin_amdgcn_s_setprio(1);
      f32x16 st0 = MFMA32(ka0, bq[0][0], zf);
      f32x16 st1 = MFMA32(ka0, bq[1][0], zf);
      st0 = MFMA32(ka1, bq[0][1], st0);
      st1 = MFMA32(ka1, bq[1][1], st1);
      st0 = MFMA32(ka2, bq[0][2], st0);
      st1 = MFMA32(ka2, bq[1][2], st1);
      st0 = MFMA32(ka3, bq[0][3], st0);
      st1 = MFMA32(ka3, bq[1][3], st1);
      __builtin_amdgcn_s_setprio(0);

      if (qany && (kb + sub * 32 + 32) > thresh) {
#pragma unroll
        for (int r = 0; r < 16; ++r) {
          int kr_ = kb + sub * 32 + (r & 3) + 8 * (r >> 2) + 4 * hi;
          if (kr_ >= thresh) {
            if (qge0) st0[r] = NEG_INF;
            if (qge1) st1[r] = NEG_INF;
          }
        }
      }

      const char* vrow0 = vbb + ql * 128;
      const char* vrow1 = vbb + (ql + 32) * 128;
      f16x8 va0 = *(const f16x8*)(vrow0 + (((sub * 4 + hi) ^ sw) * 16));
      f16x8 va1 = *(const f16x8*)(vrow0 + (((sub * 4 + 2 + hi) ^ sw) * 16));
      f16x8 va2 = *(const f16x8*)(vrow1 + (((sub * 4 + hi) ^ sw) * 16));
      f16x8 va3 = *(const f16x8*)(vrow1 + (((sub * 4 + 2 + hi) ^ sw) * 16));

#pragma unroll
      for (int qh = 0; qh < 2; ++qh) {
        const f32x16& stq = qh ? st1 : st0;
        float p[16];
#pragma unroll
        for (int r = 0; r < 16; ++r) p[r] = exp2_hw(stq[r]);

        unsigned pw[8], psum[2];
#pragma unroll
        for (int j = 0; j < 2; ++j) {
          unsigned a0 = pkrtz(p[j * 8 + 0], p[j * 8 + 1]);
          unsigned b0 = pkrtz(p[j * 8 + 4], p[j * 8 + 5]);
          unsigned a1 = pkrtz(p[j * 8 + 2], p[j * 8 + 3]);
          unsigned b1 = pkrtz(p[j * 8 + 6], p[j * 8 + 7]);
          psum[j] = pkadd(pkadd(a0, b0), pkadd(a1, b1));
          permswap(a0, b0);
          permswap(a1, b1);
          pw[j * 4 + 0] = a0; pw[j * 4 + 1] = a1;
          pw[j * 4 + 2] = b0; pw[j * 4 + 3] = b1;
        }
        {
          f16x2 ph = __builtin_bit_cast(f16x2, pkadd(psum[0], psum[1]));
          if (qh) l1 += (float)ph[0] + (float)ph[1];
          else    l0 += (float)ph[0] + (float)ph[1];
        }
        u32x4 u0 = {pw[0], pw[1], pw[2], pw[3]};
        u32x4 u1 = {pw[4], pw[5], pw[6], pw[7]};
        f16x8 pb0 = __builtin_bit_cast(f16x8, u0);
        f16x8 pb1 = __builtin_bit_cast(f16x8, u1);

        __builtin_amdgcn_s_setprio(1);
        o[qh][0] = MFMA32(va0, pb0, o[qh][0]);
        o[qh][0] = MFMA32(va1, pb1, o[qh][0]);
        o[qh][1] = MFMA32(va2, pb0, o[qh][1]);
        o[qh][1] = MFMA32(va3, pb1, o[qh][1]);
        __builtin_amdgcn_s_setprio(0);
      }
    }

    __syncthreads();
    cur ^= 1;
  }

  float lf0 = l0 + __shfl_xor(l0, 32, 64);
  float lf1 = l1 + __shfl_xor(l1, 32, 64);
  float linv0 = 1.0f / lf0;
  float linv1 = 1.0f / lf1;

  const int bb = n >> 4, hh = n & 15;
  const int qr = lane >> 3, s0 = (lane & 7) * 8;
  _Float16* my = (_Float16*)(smem + wave * 8192);
#pragma unroll
  for (int qh = 0; qh < 2; ++qh) {
    float linv = qh ? linv1 : linv0;
    _Float16* myq = my + qh * 2048;
#pragma unroll
    for (int stile = 0; stile < 2; ++stile) {
#pragma unroll
      for (int r = 0; r < 16; r += 2) {
        unsigned wv = pkrtz(o[qh][stile][r] * linv, o[qh][stile][r + 1] * linv);
        int s = stile * 32 + (r & 3) + 8 * (r >> 2) + 4 * hi;
        *(unsigned*)(myq + ql * 64 + (s ^ ((ql & 7) << 3))) = wv;
      }
    }
  }
  asm volatile("s_waitcnt lgkmcnt(0)" ::: "memory");

#pragma unroll
  for (int qh = 0; qh < 2; ++qh) {
    _Float16* myq = my + qh * 2048;
#pragma unroll
    for (int j = 0; j < 4; ++j) {
      int q = j * 8 + qr;
      f16x8 vv = *(const f16x8*)(myq + q * 64 + (s0 ^ ((q & 7) << 3)));
      *(f16x8*)(AO + ((long)(bb * Tn + qbase + qh * 32 + q)) * EMBn + hh * 64 + s0) = vv;
    }
  }
}

// --------------------------------------------------------------- oproj ----
// r14 form: 1024 blocks, 128m x 64n, lb(256,4), A-frag register dbuf.
__global__ __launch_bounds__(256, 4) void sa_oproj(
    const _Float16* __restrict__ A, const _Float16* __restrict__ WuB,
    const float* __restrict__ bu, float* __restrict__ Y) {
  const int bid = blockIdx.x;
  const int xcd = bid & 7;
  const int j = bid >> 3;             // 0..127
  const int nstrip = j & 15;
  const int mblk = xcd * 8 + (j >> 4);
  const int tid = threadIdx.x;
  const int wave = tid >> 6;
  const int lane = tid & 63;
  const int ql = lane & 31;
  const int hi = lane >> 5;
  const int mbase = mblk * 128 + wave * 32;
  const int nbase = nstrip * 64;

  __shared__ __align__(16) char bsm[18432];
  const int sr = tid >> 3, sc = tid & 7;
  const _Float16* wg0 = WuB + (long)(nbase + sr) * 1024 + sc * 8;
  const _Float16* wg1 = WuB + (long)(nbase + sr + 32) * 1024 + sc * 8;
  char* ww0 = bsm + sr * 144 + sc * 16;
  char* ww1 = bsm + (sr + 32) * 144 + sc * 16;

  const _Float16* ap = A + (long)(mbase + ql) * 1024 + hi * 8;

  f32x16 acc[2];
#pragma unroll
  for (int i = 0; i < 16; ++i) { acc[0][i] = 0.f; acc[1][i] = 0.f; }

  f16x8 af[4];
  {
    f16x8 w0 = *(const f16x8*)wg0;
    f16x8 w1 = *(const f16x8*)wg1;
    *(f16x8*)ww0 = w0;
    *(f16x8*)ww1 = w1;
#pragma unroll
    for (int ks = 0; ks < 4; ++ks) af[ks] = *(const f16x8*)(ap + ks * 16);
  }
  __syncthreads();

  int cur = 0;
  for (int kb = 0; kb < 1024; kb += 64) {
    const int kbn = (kb + 64) & 1023;
    f16x8 wn0 = *(const f16x8*)(wg0 + kbn);
    f16x8 wn1 = *(const f16x8*)(wg1 + kbn);
    f16x8 an[4];
#pragma unroll
    for (int ks = 0; ks < 4; ++ks) an[ks] = *(const f16x8*)(ap + kbn + ks * 16);

    const char* bbase = bsm + cur * 9216;
#pragma unroll
    for (int nt = 0; nt < 2; ++nt) {
      const char* brow = bbase + (nt * 32 + ql) * 144;
#pragma unroll
      for (int ks = 0; ks < 4; ++ks) {
        f16x8 bf = *(const f16x8*)(brow + (ks * 2 + hi) * 16);
        acc[nt] = MFMA32(af[ks], bf, acc[nt]);
      }
    }

    *(f16x8*)(ww0 + (cur ^ 1) * 9216) = wn0;
    *(f16x8*)(ww1 + (cur ^ 1) * 9216) = wn1;
    __syncthreads();
#pragma unroll
    for (int ks = 0; ks < 4; ++ks) af[ks] = an[ks];
    cur ^= 1;
  }

#pragma unroll
  for (int nt = 0; nt < 2; ++nt) {
    float bias = bu[nbase + nt * 32 + ql];
#pragma unroll
    for (int r = 0; r < 16; ++r) {
      int mrow = mbase + (r & 3) + 8 * (r >> 2) + 4 * hi;
      Y[(long)mrow * 1024 + nbase + nt * 32 + ql] = acc[nt][r] + bias;
    }
  }
}

// -------------------------------------------------------------- launch ----
extern "C" void kernel_launch(void* const* d_in, const int* in_sizes, int n_in,
                              void* d_out, int out_size, void* d_ws, size_t ws_size,
                              hipStream_t stream) {
  const float* x  = (const float*)d_in[0];
  const float* Wk = (const float*)d_in[1];
  const float* Wq = (const float*)d_in[2];
  const float* Wv = (const float*)d_in[3];
  const float* Wu = (const float*)d_in[4];
  const float* bu = (const float*)d_in[5];
  const int* pad  = (const int*)d_in[6];
  float* Y = (float*)d_out;

  _Float16* ws  = (_Float16*)d_ws;
  _Float16* w3  = ws;                        // 12288 (pad to 16384)
  _Float16* wub = ws + 16384;                // 1048576
  _Float16* Qb  = ws + 16384 + 1048576;      // 8388608 each
  _Float16* Kb  = Qb + 8388608;
  _Float16* Vt  = Kb + 8388608;              // V transposed: [n][s][t]
  _Float16* AO  = Vt + 8388608;

  sa_prep<<<1024, 256, 0, stream>>>(Wk, Wq, Wv, Wu, w3, wub);
  sa_qkv<<<dim3(32, 64), 256, 0, stream>>>(x, w3, Qb, Kb, Vt);
  sa_flash<<<dim3(512), 256, 0, stream>>>(Qb, Kb, Vt, pad, AO);
  sa_oproj<<<dim3(1024), 256, 0, stream>>>(AO, wub, bu, Y);
}